// Round 1
// 867.008 us; speedup vs baseline: 1.0862x; 1.0862x over previous
//
#include <hip/hip_runtime.h>
#include <hip/hip_bf16.h>

#define NB 512
#define CCH 32
#define LF 1024
#define CL (CCH * LF)  // 32768
#define BN_EPS 1e-5f

typedef __bf16 bf16x8 __attribute__((ext_vector_type(8)));
typedef __bf16 bf16x4 __attribute__((ext_vector_type(4)));
typedef float f32x4 __attribute__((ext_vector_type(4)));

// Async global->LDS, 16B per lane. LDS dest is wave-uniform base + lane*16
// (HW behavior), so LDS layout must be linear in lane order.
__device__ __forceinline__ void gload16(const void* g, void* l) {
  auto gp = (const __attribute__((address_space(1))) void*)(uintptr_t)g;
  auto lp = (__attribute__((address_space(3))) void*)(uint32_t)(uintptr_t)l;
  __builtin_amdgcn_global_load_lds(gp, lp, 16, 0, 0);
}

// x: (N, C, L) fp32 -> xb: (C, N, L) bf16
__global__ __launch_bounds__(256) void cvt_x(const float* __restrict__ x,
                                             __bf16* __restrict__ xb) {
  const int c = blockIdx.y;
  const int wv = threadIdx.x >> 6, lane = threadIdx.x & 63;
  const int n0 = blockIdx.x * 8;
#pragma unroll
  for (int rr = 0; rr < 2; ++rr) {
    const int n = n0 + wv * 2 + rr;
    const float* src = x + ((size_t)n * CCH + c) * LF;
    __bf16* dst = xb + ((size_t)c * NB + n) * LF;
#pragma unroll
    for (int j = 0; j < 4; ++j) {
      const int col = (j * 64 + lane) * 4;
      f32x4 v = *(const f32x4*)(src + col);
      bf16x4 o = {(__bf16)v.x, (__bf16)v.y, (__bf16)v.z, (__bf16)v.w};
      *(bf16x4*)(dst + col) = o;
    }
  }
}

// Fold BN affine into next layer's weights/bias:
//   W'[m,l] = bf16(W[m,l] * s[l]);  b'[m] = b[m] + sum_l W[m,l]*t[l]
// For HAS_BN=false: plain fp32->bf16 conversion + bias copy.
template <bool HAS_BN>
__global__ __launch_bounds__(256) void fold_w(
    const float* __restrict__ Wall, const float* __restrict__ ball,
    const float* __restrict__ scale, const float* __restrict__ shift,
    __bf16* __restrict__ Wb, float* __restrict__ bout, int layer) {
  const int c = blockIdx.y;
  const int wv = threadIdx.x >> 6, lane = threadIdx.x & 63;
  const float* Wp = Wall + (size_t)(c * 3 + layer) * LF * LF;
  const float* scl = scale + (size_t)c * LF;
  const float* shf = shift + (size_t)c * LF;
  const int m0 = blockIdx.x * 16 + wv * 4;
#pragma unroll
  for (int rr = 0; rr < 4; ++rr) {
    const int m = m0 + rr;
    const float* wrow = Wp + (size_t)m * LF;
    __bf16* orow = Wb + (size_t)c * LF * LF + (size_t)m * LF;
    float dot = 0.f;
#pragma unroll
    for (int j = 0; j < 4; ++j) {
      const int col = (j * 64 + lane) * 4;
      f32x4 w = *(const f32x4*)(wrow + col);
      if (HAS_BN) {
        f32x4 s = *(const f32x4*)(scl + col);
        f32x4 t = *(const f32x4*)(shf + col);
        dot += w.x * t.x + w.y * t.y + w.z * t.z + w.w * t.w;
        f32x4 wsc = w * s;
        bf16x4 o = {(__bf16)wsc.x, (__bf16)wsc.y, (__bf16)wsc.z, (__bf16)wsc.w};
        *(bf16x4*)(orow + col) = o;
      } else {
        bf16x4 o = {(__bf16)w.x, (__bf16)w.y, (__bf16)w.z, (__bf16)w.w};
        *(bf16x4*)(orow + col) = o;
      }
    }
    if (HAS_BN) {
#pragma unroll
      for (int off = 32; off >= 1; off >>= 1) dot += __shfl_down(dot, off);
    }
    if (lane == 0)
      bout[(size_t)c * LF + m] =
          ball[(size_t)(c * 3 + layer) * LF + m] + (HAS_BN ? dot : 0.f);
  }
}

// C = A @ W'^T per channel, all-bf16 operands via global_load_lds (m97
// structure: 128x128 tile, BK=32, 4 waves, linear [128][32] LDS).
// A: (C, NB, LF) bf16. Wb: (C, LF, LF) bf16 (BN-folded). bf: folded bias.
// OUTBF: write (C, NB, LF) bf16 (hidden act); else (N, C, L) fp32 (final).
template <bool RELU, bool OUTBF>
__global__ __launch_bounds__(256, 2) void gemm_k(
    const __bf16* __restrict__ Ab, const __bf16* __restrict__ Wb,
    const float* __restrict__ bf, void* __restrict__ Out) {
  __shared__ __bf16 As[128 * 32];
  __shared__ __bf16 Bs[128 * 32];
  const int tid = threadIdx.x;
  const int c = blockIdx.y;
  const int mtile = blockIdx.x & 3;   // 4 tiles over batch (512/128)
  const int ntile = blockIdx.x >> 2;  // 8 tiles over features (1024/128)

  const int lane = tid & 63;
  const int wv = tid >> 6;
  const int wm = (wv & 1) * 64;  // wave's 64x64 quadrant
  const int wn = (wv >> 1) * 64;
  const int l15 = lane & 15;
  const int quad = lane >> 4;

  // staging: lane -> (row, 16B k-segment); 4 lanes cover one row's 32 k
  const int srow = lane >> 2;       // 0..15
  const int skel = (lane & 3) * 8;  // k element offset 0,8,16,24

  const __bf16* Ag = Ab + (size_t)c * NB * LF +
                     (size_t)(mtile * 128 + wv * 32 + srow) * LF + skel;
  const __bf16* Bg = Wb + (size_t)c * LF * LF +
                     (size_t)(ntile * 128 + wv * 32 + srow) * LF + skel;
  __bf16* Al = &As[(wv * 32) * 32];  // wave-uniform LDS base
  __bf16* Bl = &Bs[(wv * 32) * 32];

  f32x4 acc[4][4] = {};

  for (int kt = 0; kt < LF / 32; ++kt) {
    const int k0 = kt * 32;
    gload16(Ag + k0, Al);
    gload16(Ag + 16 * LF + k0, Al + 16 * 32);
    gload16(Bg + k0, Bl);
    gload16(Bg + 16 * LF + k0, Bl + 16 * 32);
    __syncthreads();

    bf16x8 af[4], bfr[4];
#pragma unroll
    for (int mi = 0; mi < 4; ++mi)
      af[mi] = *(const bf16x8*)&As[(wm + mi * 16 + l15) * 32 + quad * 8];
#pragma unroll
    for (int ni = 0; ni < 4; ++ni)
      bfr[ni] = *(const bf16x8*)&Bs[(wn + ni * 16 + l15) * 32 + quad * 8];
#pragma unroll
    for (int mi = 0; mi < 4; ++mi)
#pragma unroll
      for (int ni = 0; ni < 4; ++ni)
        acc[mi][ni] = __builtin_amdgcn_mfma_f32_16x16x32_bf16(
            af[mi], bfr[ni], acc[mi][ni], 0, 0, 0);
    __syncthreads();
  }

  // epilogue: D row (batch) = quad*4 + r, col (feature) = lane&15
  const float* bias = bf + (size_t)c * LF;
  if (OUTBF) {
    __bf16* outp = (__bf16*)Out + (size_t)c * NB * LF;
#pragma unroll
    for (int ni = 0; ni < 4; ++ni) {
      const int feat = ntile * 128 + wn + ni * 16 + l15;
      const float bvv = bias[feat];
#pragma unroll
      for (int mi = 0; mi < 4; ++mi) {
        const int row0 = mtile * 128 + wm + mi * 16 + quad * 4;
#pragma unroll
        for (int r = 0; r < 4; ++r) {
          float v = acc[mi][ni][r] + bvv;
          if (RELU) v = fmaxf(v, 0.f);
          outp[(size_t)(row0 + r) * LF + feat] = (__bf16)v;
        }
      }
    }
  } else {
    float* outp = (float*)Out + (size_t)c * LF;
#pragma unroll
    for (int ni = 0; ni < 4; ++ni) {
      const int feat = ntile * 128 + wn + ni * 16 + l15;
      const float bvv = bias[feat];
#pragma unroll
      for (int mi = 0; mi < 4; ++mi) {
        const int row0 = mtile * 128 + wm + mi * 16 + quad * 4;
#pragma unroll
        for (int r = 0; r < 4; ++r) {
          float v = acc[mi][ni][r] + bvv;
          if (RELU) v = fmaxf(v, 0.f);
          outp[(size_t)(row0 + r) * CL + feat] = v;
        }
      }
    }
  }
}

// Batch stats over bf16 activations (C, NB, LF); emits fused affine
// scale = rstd*gamma, shift = beta - mean*scale. Biased variance.
__global__ __launch_bounds__(256) void bn_stats(
    const __bf16* __restrict__ H, const float* __restrict__ gamma,
    const float* __restrict__ beta, float* __restrict__ scale,
    float* __restrict__ shift, int bnlayer) {
  __shared__ float s_sum[256], s_sq[256];
  const int tid = threadIdx.x;
  const int f = tid & 63, g = tid >> 6;
  const int c = blockIdx.y;
  const int l = blockIdx.x * 64 + f;
  const __bf16* col = H + (size_t)c * NB * LF + l;
  float sum = 0.f, sq = 0.f;
  for (int n = g; n < NB; n += 4) {
    float v = (float)col[(size_t)n * LF];
    sum += v;
    sq += v * v;
  }
  s_sum[tid] = sum;
  s_sq[tid] = sq;
  __syncthreads();
  if (g == 0) {
    sum = s_sum[f] + s_sum[64 + f] + s_sum[128 + f] + s_sum[192 + f];
    sq = s_sq[f] + s_sq[64 + f] + s_sq[128 + f] + s_sq[192 + f];
    const float mean = sum * (1.f / NB);
    const float var = sq * (1.f / NB) - mean * mean;
    const float rstd = rsqrtf(var + BN_EPS);
    const float ga = gamma[(size_t)(c * 2 + bnlayer) * LF + l];
    const float be = beta[(size_t)(c * 2 + bnlayer) * LF + l];
    const float sc = rstd * ga;
    scale[(size_t)c * LF + l] = sc;
    shift[(size_t)c * LF + l] = be - mean * sc;
  }
}

extern "C" void kernel_launch(void* const* d_in, const int* in_sizes, int n_in,
                              void* d_out, int out_size, void* d_ws,
                              size_t ws_size, hipStream_t stream) {
  const float* x = (const float*)d_in[0];
  const float* W = (const float*)d_in[1];
  const float* b = (const float*)d_in[2];
  const float* gamma = (const float*)d_in[3];
  const float* beta = (const float*)d_in[4];
  float* out = (float*)d_out;

  // ws: scale | shift | bfold (128 KB each) | xb | h1 | h2 (32 MB bf16 each)
  //     | Wfold (64 MB bf16)
  char* ws = (char*)d_ws;
  float* scale = (float*)ws;  ws += (size_t)CL * 4;
  float* shift = (float*)ws;  ws += (size_t)CL * 4;
  float* bfold = (float*)ws;  ws += (size_t)CL * 4;
  __bf16* xb = (__bf16*)ws;   ws += (size_t)NB * CL * 2;
  __bf16* h1 = (__bf16*)ws;   ws += (size_t)NB * CL * 2;
  __bf16* h2 = (__bf16*)ws;   ws += (size_t)NB * CL * 2;
  __bf16* Wfold = (__bf16*)ws;

  const dim3 blk(256);
  const dim3 ggrid(32, 32);  // 4 m-tiles * 8 n-tiles, 32 channels
  const dim3 fgrid(64, 32);  // 1024/16 row-groups, 32 channels
  const dim3 sgrid(16, 32);  // 1024 features / 64, 32 channels

  cvt_x<<<fgrid, blk, 0, stream>>>(x, xb);
  // layer 0: h1 = relu(xb @ bf16(W0)^T + b0)
  fold_w<false><<<fgrid, blk, 0, stream>>>(W, b, scale, shift, Wfold, bfold, 0);
  gemm_k<true, true><<<ggrid, blk, 0, stream>>>(xb, Wfold, bfold, h1);
  bn_stats<<<sgrid, blk, 0, stream>>>(h1, gamma, beta, scale, shift, 0);
  // layer 1: h2 = relu(h1 @ (W1*s0)^T + (b1 + W1@t0))
  fold_w<true><<<fgrid, blk, 0, stream>>>(W, b, scale, shift, Wfold, bfold, 1);
  gemm_k<true, true><<<ggrid, blk, 0, stream>>>(h1, Wfold, bfold, h2);
  bn_stats<<<sgrid, blk, 0, stream>>>(h2, gamma, beta, scale, shift, 1);
  // layer 2: out = h2 @ (W2*s1)^T + (b2 + W2@t1)  (fp32, (N,C,L))
  fold_w<true><<<fgrid, blk, 0, stream>>>(W, b, scale, shift, Wfold, bfold, 2);
  gemm_k<false, false><<<ggrid, blk, 0, stream>>>(h2, Wfold, bfold, out);
}

// Round 2
// 863.647 us; speedup vs baseline: 1.0904x; 1.0039x over previous
//
#include <hip/hip_runtime.h>
#include <hip/hip_bf16.h>

#define NB 512
#define CCH 32
#define LF 1024
#define CL (CCH * LF)  // 32768
#define BN_EPS 1e-5f

typedef __bf16 bf16x8 __attribute__((ext_vector_type(8)));
typedef __bf16 bf16x4 __attribute__((ext_vector_type(4)));
typedef float f32x4 __attribute__((ext_vector_type(4)));

// Async global->LDS, 16B per lane. LDS dest is wave-uniform base + lane*16
// (HW behavior), so LDS layout must be linear in lane order.
__device__ __forceinline__ void gload16(const void* g, void* l) {
  auto gp = (const __attribute__((address_space(1))) void*)(uintptr_t)g;
  auto lp = (__attribute__((address_space(3))) void*)(uint32_t)(uintptr_t)l;
  __builtin_amdgcn_global_load_lds(gp, lp, 16, 0, 0);
}

// x: (N, C, L) fp32 -> xb: (C, N, L) bf16
__global__ __launch_bounds__(256) void cvt_x(const float* __restrict__ x,
                                             __bf16* __restrict__ xb) {
  const int c = blockIdx.y;
  const int wv = threadIdx.x >> 6, lane = threadIdx.x & 63;
  const int n0 = blockIdx.x * 8;
#pragma unroll
  for (int rr = 0; rr < 2; ++rr) {
    const int n = n0 + wv * 2 + rr;
    const float* src = x + ((size_t)n * CCH + c) * LF;
    __bf16* dst = xb + ((size_t)c * NB + n) * LF;
#pragma unroll
    for (int j = 0; j < 4; ++j) {
      const int col = (j * 64 + lane) * 4;
      f32x4 v = *(const f32x4*)(src + col);
      bf16x4 o = {(__bf16)v.x, (__bf16)v.y, (__bf16)v.z, (__bf16)v.w};
      *(bf16x4*)(dst + col) = o;
    }
  }
}

// One-time fp32 -> bf16 conversion of ALL layer weights (no BN dependency).
// Wall: (C, 3, L, L) fp32; Wb: same layout bf16. slab = c*3+layer.
__global__ __launch_bounds__(256) void cvt_w(const float* __restrict__ Wall,
                                             __bf16* __restrict__ Wb) {
  const int slab = blockIdx.y;
  const int wv = threadIdx.x >> 6, lane = threadIdx.x & 63;
  const float* Wp = Wall + (size_t)slab * LF * LF;
  __bf16* Op = Wb + (size_t)slab * LF * LF;
  const int m0 = blockIdx.x * 16 + wv * 4;
#pragma unroll
  for (int rr = 0; rr < 4; ++rr) {
    const int m = m0 + rr;
    const float* wrow = Wp + (size_t)m * LF;
    __bf16* orow = Op + (size_t)m * LF;
#pragma unroll
    for (int j = 0; j < 4; ++j) {
      const int col = (j * 64 + lane) * 4;
      f32x4 w = *(const f32x4*)(wrow + col);
      bf16x4 o = {(__bf16)w.x, (__bf16)w.y, (__bf16)w.z, (__bf16)w.w};
      *(bf16x4*)(orow + col) = o;
    }
  }
}

// C = A @ W^T per channel, all-bf16 operands via global_load_lds (m97
// structure: 128x128 tile, BK=32, 4 waves, linear [128][32] LDS).
// A: (C, NB, LF) bf16 (already BN-normalized if applicable).
// Wb: (C, 3, LF, LF) bf16. ball: raw fp32 bias (C, 3, LF).
// Grid is 1-D 1024 with XCD-affinity decomposition: all 32 tiles of a
// channel land on one XCD (bid%8 constant), so its ~3 MB working set
// (1 MB A + 2 MB W) L2-hits instead of being fetched by 4 XCDs.
template <bool RELU, bool OUTBF>
__global__ __launch_bounds__(256, 2) void gemm_k(
    const __bf16* __restrict__ Ab, const __bf16* __restrict__ Wb,
    const float* __restrict__ ball, void* __restrict__ Out, int layer) {
  __shared__ __bf16 As[128 * 32];
  __shared__ __bf16 Bs[128 * 32];
  const int tid = threadIdx.x;
  const int bid = blockIdx.x;
  const int c = (bid & 7) | ((bid >> 8) << 3);  // XCD-affine channel
  const int tile = (bid >> 3) & 31;
  const int mtile = tile & 3;   // 4 tiles over batch (512/128)
  const int ntile = tile >> 2;  // 8 tiles over features (1024/128)

  const int lane = tid & 63;
  const int wv = tid >> 6;
  const int wm = (wv & 1) * 64;  // wave's 64x64 quadrant
  const int wn = (wv >> 1) * 64;
  const int l15 = lane & 15;
  const int quad = lane >> 4;

  // staging: lane -> (row, 16B k-segment); 4 lanes cover one row's 32 k
  const int srow = lane >> 2;       // 0..15
  const int skel = (lane & 3) * 8;  // k element offset 0,8,16,24

  const __bf16* Ag = Ab + (size_t)c * NB * LF +
                     (size_t)(mtile * 128 + wv * 32 + srow) * LF + skel;
  const __bf16* Bg = Wb + (size_t)(c * 3 + layer) * LF * LF +
                     (size_t)(ntile * 128 + wv * 32 + srow) * LF + skel;
  __bf16* Al = &As[(wv * 32) * 32];  // wave-uniform LDS base
  __bf16* Bl = &Bs[(wv * 32) * 32];

  f32x4 acc[4][4] = {};

  for (int kt = 0; kt < LF / 32; ++kt) {
    const int k0 = kt * 32;
    gload16(Ag + k0, Al);
    gload16(Ag + 16 * LF + k0, Al + 16 * 32);
    gload16(Bg + k0, Bl);
    gload16(Bg + 16 * LF + k0, Bl + 16 * 32);
    __syncthreads();

    bf16x8 af[4], bfr[4];
#pragma unroll
    for (int mi = 0; mi < 4; ++mi)
      af[mi] = *(const bf16x8*)&As[(wm + mi * 16 + l15) * 32 + quad * 8];
#pragma unroll
    for (int ni = 0; ni < 4; ++ni)
      bfr[ni] = *(const bf16x8*)&Bs[(wn + ni * 16 + l15) * 32 + quad * 8];
#pragma unroll
    for (int mi = 0; mi < 4; ++mi)
#pragma unroll
      for (int ni = 0; ni < 4; ++ni)
        acc[mi][ni] = __builtin_amdgcn_mfma_f32_16x16x32_bf16(
            af[mi], bfr[ni], acc[mi][ni], 0, 0, 0);
    __syncthreads();
  }

  // epilogue: D row (batch) = quad*4 + r, col (feature) = lane&15
  const float* bias = ball + (size_t)(c * 3 + layer) * LF;
  if (OUTBF) {
    __bf16* outp = (__bf16*)Out + (size_t)c * NB * LF;
#pragma unroll
    for (int ni = 0; ni < 4; ++ni) {
      const int feat = ntile * 128 + wn + ni * 16 + l15;
      const float bvv = bias[feat];
#pragma unroll
      for (int mi = 0; mi < 4; ++mi) {
        const int row0 = mtile * 128 + wm + mi * 16 + quad * 4;
#pragma unroll
        for (int r = 0; r < 4; ++r) {
          float v = acc[mi][ni][r] + bvv;
          if (RELU) v = fmaxf(v, 0.f);
          outp[(size_t)(row0 + r) * LF + feat] = (__bf16)v;
        }
      }
    }
  } else {
    float* outp = (float*)Out + (size_t)c * LF;
#pragma unroll
    for (int ni = 0; ni < 4; ++ni) {
      const int feat = ntile * 128 + wn + ni * 16 + l15;
      const float bvv = bias[feat];
#pragma unroll
      for (int mi = 0; mi < 4; ++mi) {
        const int row0 = mtile * 128 + wm + mi * 16 + quad * 4;
#pragma unroll
        for (int r = 0; r < 4; ++r) {
          float v = acc[mi][ni][r] + bvv;
          if (RELU) v = fmaxf(v, 0.f);
          outp[(size_t)(row0 + r) * CL + feat] = v;
        }
      }
    }
  }
}

// Fused BN: batch stats over bf16 activations (C, NB, LF) + normalize.
// Hn = H*scale + shift with scale = rstd*gamma, shift = beta - mean*scale.
// Biased variance (matches torch BN). Writes to a SEPARATE buffer (not
// in-place) so rocprof kernel replay can't double-apply.
__global__ __launch_bounds__(256) void bn_norm(
    const __bf16* __restrict__ H, const float* __restrict__ gamma,
    const float* __restrict__ beta, __bf16* __restrict__ Hn, int bnlayer) {
  __shared__ float s_sum[256], s_sq[256];
  __shared__ float s_sc[64], s_sh[64];
  const int tid = threadIdx.x;
  const int f = tid & 63, g = tid >> 6;
  const int c = blockIdx.y;
  const int l = blockIdx.x * 64 + f;
  const __bf16* col = H + (size_t)c * NB * LF + l;
  float sum = 0.f, sq = 0.f;
  for (int n = g; n < NB; n += 4) {
    float v = (float)col[(size_t)n * LF];
    sum += v;
    sq += v * v;
  }
  s_sum[tid] = sum;
  s_sq[tid] = sq;
  __syncthreads();
  if (g == 0) {
    sum = s_sum[f] + s_sum[64 + f] + s_sum[128 + f] + s_sum[192 + f];
    sq = s_sq[f] + s_sq[64 + f] + s_sq[128 + f] + s_sq[192 + f];
    const float mean = sum * (1.f / NB);
    const float var = sq * (1.f / NB) - mean * mean;
    const float rstd = rsqrtf(var + BN_EPS);
    const float ga = gamma[(size_t)(c * 2 + bnlayer) * LF + l];
    const float be = beta[(size_t)(c * 2 + bnlayer) * LF + l];
    const float sc = rstd * ga;
    s_sc[f] = sc;
    s_sh[f] = be - mean * sc;
  }
  __syncthreads();
  const float sc = s_sc[f];
  const float sh = s_sh[f];
  __bf16* ocol = Hn + (size_t)c * NB * LF + l;
  for (int n = g; n < NB; n += 4) {
    float v = (float)col[(size_t)n * LF];
    ocol[(size_t)n * LF] = (__bf16)(v * sc + sh);
  }
}

extern "C" void kernel_launch(void* const* d_in, const int* in_sizes, int n_in,
                              void* d_out, int out_size, void* d_ws,
                              size_t ws_size, hipStream_t stream) {
  const float* x = (const float*)d_in[0];
  const float* W = (const float*)d_in[1];
  const float* b = (const float*)d_in[2];
  const float* gamma = (const float*)d_in[3];
  const float* beta = (const float*)d_in[4];
  float* out = (float*)d_out;

  // ws: xb | h1 | h1n | h2 | h2n (32 MB bf16 each) | Wb (192 MB bf16)
  char* ws = (char*)d_ws;
  __bf16* xb = (__bf16*)ws;   ws += (size_t)NB * CL * 2;
  __bf16* h1 = (__bf16*)ws;   ws += (size_t)NB * CL * 2;
  __bf16* h1n = (__bf16*)ws;  ws += (size_t)NB * CL * 2;
  __bf16* h2 = (__bf16*)ws;   ws += (size_t)NB * CL * 2;
  __bf16* h2n = (__bf16*)ws;  ws += (size_t)NB * CL * 2;
  __bf16* Wb = (__bf16*)ws;

  const dim3 blk(256);
  const dim3 cgrid(64, 32);  // cvt_x: 512/8 batch-groups, 32 channels
  const dim3 wgrid(64, 96);  // cvt_w: 1024/16 row-groups, 96 slabs
  const dim3 sgrid(16, 32);  // bn: 1024 features / 64, 32 channels
  const int ggrid = 1024;    // gemm: 32 tiles * 32 channels, XCD-swizzled

  cvt_x<<<cgrid, blk, 0, stream>>>(x, xb);
  cvt_w<<<wgrid, blk, 0, stream>>>(W, Wb);
  // layer 0: h1 = relu(xb @ W0^T + b0)
  gemm_k<true, true><<<ggrid, blk, 0, stream>>>(xb, Wb, b, h1, 0);
  bn_norm<<<sgrid, blk, 0, stream>>>(h1, gamma, beta, h1n, 0);
  // layer 1: h2 = relu(h1n @ W1^T + b1)
  gemm_k<true, true><<<ggrid, blk, 0, stream>>>(h1n, Wb, b, h2, 1);
  bn_norm<<<sgrid, blk, 0, stream>>>(h2, gamma, beta, h2n, 1);
  // layer 2: out = h2n @ W2^T + b2  (fp32, (N,C,L))
  gemm_k<false, false><<<ggrid, blk, 0, stream>>>(h2n, Wb, b, out, 2);
}

// Round 4
// 825.938 us; speedup vs baseline: 1.1402x; 1.0457x over previous
//
#include <hip/hip_runtime.h>
#include <hip/hip_bf16.h>

#define NB 512
#define CCH 32
#define LF 1024
#define CL (CCH * LF)  // 32768
#define BN_EPS 1e-5f
#define LSE 40  // LDS row stride in bf16 elems (80 B): 2-way banks, 16B-aligned

typedef __bf16 bf16x8 __attribute__((ext_vector_type(8)));
typedef __bf16 bf16x4 __attribute__((ext_vector_type(4)));
typedef float f32x4 __attribute__((ext_vector_type(4)));

// C = A @ W^T per channel. 128x128 tile, BK=32, 4 waves, 2-phase
// double-buffered K-loop: kt+1 global loads issue BEFORE kt's MFMAs,
// convert+LDS-write after (T14 issue-early/write-late), one barrier/step.
// A is reg-staged (fp32 x for layer 0 / bf16 h with fused BN affine for
// layers 1-2) and converted to bf16 during staging. B is reg-staged fp32 W
// (C,3,LF,LF) converted in-register. Both LDS tiles use padded 80B rows.
template <bool AF32, bool BNA, bool RELU, bool OUTBF>
__global__ __launch_bounds__(256, 2) void gemm_k(
    const void* __restrict__ Ain, const float* __restrict__ W,
    const float* __restrict__ ball, const float* __restrict__ scale,
    const float* __restrict__ shift, void* __restrict__ Out, int layer) {
  __shared__ __bf16 As[2 * 128 * LSE];  // 20 KB
  __shared__ __bf16 Bs[2 * 128 * LSE];  // 20 KB

  const int tid = threadIdx.x;
  const int bid = blockIdx.x;
  const int c = (bid & 7) | ((bid >> 8) << 3);  // XCD-affine channel
  const int tile = (bid >> 3) & 31;
  const int mtile = tile & 3;   // 4 tiles over batch (512/128)
  const int ntile = tile >> 2;  // 8 tiles over features (1024/128)

  const int lane = tid & 63, wv = tid >> 6;
  const int wm = (wv & 1) * 64, wn = (wv >> 1) * 64;
  const int l15 = lane & 15, quad = lane >> 4;

  // A staging: thread -> (row sr 0..31 per 32-row group, 4-elem k-seg kseg)
  const int sr = tid >> 3, kseg = tid & 7;
  // B staging: wave wv covers rows wv*32..wv*32+31; fl = j*64+lane
  const float* Wp =
      W + ((size_t)(c * 3 + layer) * LF + ntile * 128 + wv * 32) * LF;

  const float* Axf = (const float*)Ain + (size_t)c * LF;            // (N,C,L)
  const __bf16* Axb = (const __bf16*)Ain + (size_t)c * NB * LF;     // (C,N,L)
  const float* scl = BNA ? scale + (size_t)c * LF + kseg * 4 : nullptr;
  const float* shf = BNA ? shift + (size_t)c * LF + kseg * 4 : nullptr;

  f32x4 acc[4][4] = {};
  f32x4 va[4], vb[4], sc, sh;

  // ---- staging helpers (macros keep all indexing compile-time) ----
#define LOADA(k0)                                                           \
  {                                                                         \
    _Pragma("unroll") for (int i = 0; i < 4; ++i) {                         \
      const int r = mtile * 128 + i * 32 + sr;                              \
      if (AF32) {                                                           \
        va[i] = *(const f32x4*)(Axf + (size_t)r * CL + (k0) + kseg * 4);    \
      } else {                                                              \
        bf16x4 t = *(const bf16x4*)(Axb + (size_t)r * LF + (k0) + kseg * 4);\
        va[i] = f32x4{(float)t[0], (float)t[1], (float)t[2], (float)t[3]};  \
      }                                                                     \
    }                                                                       \
    if (BNA) {                                                              \
      sc = *(const f32x4*)(scl + (k0));                                     \
      sh = *(const f32x4*)(shf + (k0));                                     \
    }                                                                       \
  }
#define LOADB(k0)                                                           \
  {                                                                         \
    _Pragma("unroll") for (int j = 0; j < 4; ++j) {                         \
      const int fl = j * 64 + lane;                                         \
      vb[j] =                                                               \
          *(const f32x4*)(Wp + (size_t)(fl >> 3) * LF + (k0) + (fl & 7) * 4);\
    }                                                                       \
  }
#define WRITEAB(dstA, dstB)                                                 \
  {                                                                         \
    _Pragma("unroll") for (int i = 0; i < 4; ++i) {                         \
      f32x4 v = va[i];                                                      \
      if (BNA) v = v * sc + sh;                                             \
      bf16x4 o = {(__bf16)v[0], (__bf16)v[1], (__bf16)v[2], (__bf16)v[3]};  \
      *(bf16x4*)&(dstA)[(i * 32 + sr) * LSE + kseg * 4] = o;                \
    }                                                                       \
    _Pragma("unroll") for (int j = 0; j < 4; ++j) {                         \
      const int fl = j * 64 + lane;                                         \
      f32x4 w = vb[j];                                                      \
      bf16x4 o = {(__bf16)w[0], (__bf16)w[1], (__bf16)w[2], (__bf16)w[3]};  \
      *(bf16x4*)&(dstB)[(wv * 32 + (fl >> 3)) * LSE + (fl & 7) * 4] = o;    \
    }                                                                       \
  }

  // prologue: stage kt=0 into buffer 0
  LOADA(0);
  LOADB(0);
  WRITEAB(As, Bs);
  __syncthreads();

  int buf = 0;
  for (int kt = 0; kt < 32; ++kt) {
    if (kt < 31) {  // issue next K-step's global loads before compute
      const int k0n = (kt + 1) * 32;
      LOADA(k0n);
      LOADB(k0n);
    }
    const __bf16* Ac = As + buf * (128 * LSE);
    const __bf16* Bc = Bs + buf * (128 * LSE);
    bf16x8 af[4], bfr[4];
#pragma unroll
    for (int mi = 0; mi < 4; ++mi)
      af[mi] = *(const bf16x8*)&Ac[(wm + mi * 16 + l15) * LSE + quad * 8];
#pragma unroll
    for (int ni = 0; ni < 4; ++ni)
      bfr[ni] = *(const bf16x8*)&Bc[(wn + ni * 16 + l15) * LSE + quad * 8];
#pragma unroll
    for (int mi = 0; mi < 4; ++mi)
#pragma unroll
      for (int ni = 0; ni < 4; ++ni)
        acc[mi][ni] = __builtin_amdgcn_mfma_f32_16x16x32_bf16(
            af[mi], bfr[ni], acc[mi][ni], 0, 0, 0);
    if (kt < 31) {  // convert + LDS-write next tile after compute
      __bf16* An = As + (buf ^ 1) * (128 * LSE);
      __bf16* Bn = Bs + (buf ^ 1) * (128 * LSE);
      WRITEAB(An, Bn);
    }
    __syncthreads();
    buf ^= 1;
  }

  // epilogue: D row (batch) = quad*4 + r, col (feature) = lane&15
  const float* bias = ball + (size_t)(c * 3 + layer) * LF;
  if (OUTBF) {
    __bf16* outp = (__bf16*)Out + (size_t)c * NB * LF;
#pragma unroll
    for (int ni = 0; ni < 4; ++ni) {
      const int feat = ntile * 128 + wn + ni * 16 + l15;
      const float bvv = bias[feat];
#pragma unroll
      for (int mi = 0; mi < 4; ++mi) {
        const int row0 = mtile * 128 + wm + mi * 16 + quad * 4;
#pragma unroll
        for (int r = 0; r < 4; ++r) {
          float vv = acc[mi][ni][r] + bvv;
          if (RELU) vv = fmaxf(vv, 0.f);
          outp[(size_t)(row0 + r) * LF + feat] = (__bf16)vv;
        }
      }
    }
  } else {
    float* outp = (float*)Out + (size_t)c * LF;
#pragma unroll
    for (int ni = 0; ni < 4; ++ni) {
      const int feat = ntile * 128 + wn + ni * 16 + l15;
      const float bvv = bias[feat];
#pragma unroll
      for (int mi = 0; mi < 4; ++mi) {
        const int row0 = mtile * 128 + wm + mi * 16 + quad * 4;
#pragma unroll
        for (int r = 0; r < 4; ++r) {
          float vv = acc[mi][ni][r] + bvv;
          if (RELU) vv = fmaxf(vv, 0.f);
          outp[(size_t)(row0 + r) * CL + feat] = vv;
        }
      }
    }
  }
#undef LOADA
#undef LOADB
#undef WRITEAB
}

// Per-(c,feature) batch stats over bf16 H (C,NB,LF); emits fused affine
// scale = rstd*gamma, shift = beta - mean*scale. Biased variance.
__global__ __launch_bounds__(256) void bn_stats(
    const __bf16* __restrict__ H, const float* __restrict__ gamma,
    const float* __restrict__ beta, float* __restrict__ scale,
    float* __restrict__ shift, int bnlayer) {
  __shared__ float s_sum[256], s_sq[256];
  const int tid = threadIdx.x;
  const int f = tid & 63, g = tid >> 6;
  const int c = blockIdx.y;
  const int l = blockIdx.x * 64 + f;
  const __bf16* col = H + (size_t)c * NB * LF + l;
  float sum = 0.f, sq = 0.f;
  for (int n = g; n < NB; n += 4) {
    float v = (float)col[(size_t)n * LF];
    sum += v;
    sq += v * v;
  }
  s_sum[tid] = sum;
  s_sq[tid] = sq;
  __syncthreads();
  if (g == 0) {
    sum = s_sum[f] + s_sum[64 + f] + s_sum[128 + f] + s_sum[192 + f];
    sq = s_sq[f] + s_sq[64 + f] + s_sq[128 + f] + s_sq[192 + f];
    const float mean = sum * (1.f / NB);
    const float var = sq * (1.f / NB) - mean * mean;
    const float rstd = rsqrtf(var + BN_EPS);
    const float ga = gamma[(size_t)(c * 2 + bnlayer) * LF + l];
    const float be = beta[(size_t)(c * 2 + bnlayer) * LF + l];
    const float sc = rstd * ga;
    scale[(size_t)c * LF + l] = sc;
    shift[(size_t)c * LF + l] = be - mean * sc;
  }
}

extern "C" void kernel_launch(void* const* d_in, const int* in_sizes, int n_in,
                              void* d_out, int out_size, void* d_ws,
                              size_t ws_size, hipStream_t stream) {
  const float* x = (const float*)d_in[0];
  const float* W = (const float*)d_in[1];
  const float* b = (const float*)d_in[2];
  const float* gamma = (const float*)d_in[3];
  const float* beta = (const float*)d_in[4];
  float* out = (float*)d_out;

  // ws: scale | shift (128 KB each) | h1 | h2 (32 MB bf16 each)
  char* ws = (char*)d_ws;
  float* scale = (float*)ws;  ws += (size_t)CL * 4;
  float* shift = (float*)ws;  ws += (size_t)CL * 4;
  __bf16* h1 = (__bf16*)ws;   ws += (size_t)NB * CL * 2;
  __bf16* h2 = (__bf16*)ws;

  const dim3 blk(256);
  const int ggrid = 1024;    // 32 tiles * 32 channels, XCD-affine
  const dim3 sgrid(16, 32);  // bn: 1024 features / 64, 32 channels

  // layer 0: h1 = relu(x @ W0^T + b0)   (A = fp32 x, (N,C,L))
  gemm_k<true, false, true, true>
      <<<ggrid, blk, 0, stream>>>(x, W, b, nullptr, nullptr, h1, 0);
  bn_stats<<<sgrid, blk, 0, stream>>>(h1, gamma, beta, scale, shift, 0);
  // layer 1: h2 = relu(BN0(h1) @ W1^T + b1)   (BN fused into A-staging)
  gemm_k<false, true, true, true>
      <<<ggrid, blk, 0, stream>>>(h1, W, b, scale, shift, h2, 1);
  bn_stats<<<sgrid, blk, 0, stream>>>(h2, gamma, beta, scale, shift, 1);
  // layer 2: out = BN1(h2) @ W2^T + b2   (fp32, (N,C,L))
  gemm_k<false, true, false, false>
      <<<ggrid, blk, 0, stream>>>(h2, W, b, scale, shift, out, 2);
}